// Round 1
// baseline (253.372 us; speedup 1.0000x reference)
//
#include <hip/hip_runtime.h>
#include <math.h>

#define N_ 2
#define L_ 2048
#define S_ 2048
#define H_ 8
#define D_ 64
#define BL 64
#define BS 64
#define SSPLIT 2
#define LDSS 68   // 64 + 4 pad: keeps 16B alignment, breaks bank aliasing

__device__ __forceinline__ float feat(float x) {
    // elu(x)+1 = x>0 ? x+1 : exp(x)
    return x > 0.0f ? x + 1.0f : __expf(x);
}

__global__ __launch_bounds__(256) void ksum_kernel(const float* __restrict__ K,
        const float* __restrict__ kvmask, float* __restrict__ Ksum) {
    int nh = blockIdx.x;
    int z = blockIdx.y;           // 8 chunks of 256 s-rows
    int n = nh / H_, h = nh % H_;
    int t = threadIdx.x;
    int d = t & 63, sc = t >> 6;  // sc in 0..3
    float sum = 0.f;
    int s0 = z * 256 + sc * 64;
    for (int k = 0; k < 64; ++k) {
        int s = s0 + k;
        float v = K[(((size_t)n * S_ + s) * H_ + h) * D_ + d];
        sum += feat(v) * kvmask[n * S_ + s];
    }
    __shared__ float sm[256];
    sm[t] = sum;
    __syncthreads();
    if (t < 64) {
        float tot = sm[t] + sm[t + 64] + sm[t + 128] + sm[t + 192];
        atomicAdd(&Ksum[nh * 64 + t], tot);
    }
}

__global__ __launch_bounds__(256) void rowmax_kernel(
        const float* __restrict__ Q, const float* __restrict__ K,
        const float* __restrict__ qmask, const float* __restrict__ kvmask,
        float* __restrict__ rowmax) {
    __shared__ float Qs[BL * LDSS];
    __shared__ float Ks[BS * LDSS];
    __shared__ float red[64 * 17];

    int ltile = blockIdx.x;                 // 0..31
    int nh = blockIdx.y;                    // 0..15
    int n = nh / H_, h = nh % H_;
    int z = blockIdx.z;                     // 0..SSPLIT-1
    int t = threadIdx.x;
    int tx = t & 15, ty = t >> 4;
    int lbase = ltile * BL;

    // ---- load + featurize Q tile (once per block) ----
    {
        const float* qb = Q + (((size_t)n * L_ + lbase) * H_ + h) * D_;
        #pragma unroll
        for (int k = 0; k < 4; ++k) {
            int idx = t + 256 * k;          // 0..1023 float4 slots
            int row = idx >> 4, c4 = (idx & 15) * 4;
            float4 v = *(const float4*)(qb + (size_t)row * (H_ * D_) + c4);
            float qm = qmask[n * L_ + lbase + row];
            float4 f;
            f.x = feat(v.x) * qm; f.y = feat(v.y) * qm;
            f.z = feat(v.z) * qm; f.w = feat(v.w) * qm;
            *(float4*)(&Qs[row * LDSS + c4]) = f;
        }
    }

    float rmax[4] = {0.f, 0.f, 0.f, 0.f};

    const int tiles = S_ / SSPLIT / BS;     // 16
    int stile0 = z * tiles;
    for (int tile = 0; tile < tiles; ++tile) {
        int sbase = (stile0 + tile) * BS;
        __syncthreads();                    // Ks reuse hazard (also covers Qs store on iter 0)
        const float* kb = K + (((size_t)n * S_ + sbase) * H_ + h) * D_;
        #pragma unroll
        for (int k = 0; k < 4; ++k) {
            int idx = t + 256 * k;
            int row = idx >> 4, c4 = (idx & 15) * 4;
            float4 v = *(const float4*)(kb + (size_t)row * (H_ * D_) + c4);
            float km = kvmask[n * S_ + sbase + row];
            float4 f;
            f.x = feat(v.x) * km; f.y = feat(v.y) * km;
            f.z = feat(v.z) * km; f.w = feat(v.w) * km;
            *(float4*)(&Ks[row * LDSS + c4]) = f;
        }
        __syncthreads();

        float acc[4][4];
        #pragma unroll
        for (int i = 0; i < 4; ++i)
            #pragma unroll
            for (int j = 0; j < 4; ++j) acc[i][j] = 0.f;

        #pragma unroll
        for (int ds = 0; ds < D_ / 4; ++ds) {
            float4 a[4], bb[4];
            #pragma unroll
            for (int i = 0; i < 4; ++i)
                a[i] = *(const float4*)&Qs[(ty + 16 * i) * LDSS + ds * 4];
            #pragma unroll
            for (int j = 0; j < 4; ++j)
                bb[j] = *(const float4*)&Ks[(tx + 16 * j) * LDSS + ds * 4];
            #pragma unroll
            for (int i = 0; i < 4; ++i)
                #pragma unroll
                for (int j = 0; j < 4; ++j) {
                    acc[i][j] += a[i].x * bb[j].x + a[i].y * bb[j].y
                               + a[i].z * bb[j].z + a[i].w * bb[j].w;
                }
        }

        #pragma unroll
        for (int i = 0; i < 4; ++i) {
            float m = fmaxf(fmaxf(acc[i][0], acc[i][1]),
                            fmaxf(acc[i][2], acc[i][3]));
            rmax[i] = fmaxf(rmax[i], m);
        }
    }

    // reduce partial row-maxes across the 16 tx columns
    #pragma unroll
    for (int i = 0; i < 4; ++i)
        red[(ty + 16 * i) * 17 + tx] = rmax[i];
    __syncthreads();
    if (t < 64) {
        float m = 0.f;
        #pragma unroll
        for (int x = 0; x < 16; ++x) m = fmaxf(m, red[t * 17 + x]);
        // all dot products >= 0 -> uint compare is order-preserving
        atomicMax((unsigned int*)&rowmax[(size_t)nh * L_ + lbase + t],
                  __float_as_uint(m));
    }
}

__global__ __launch_bounds__(256) void finalize_kernel(
        const float* __restrict__ Q, const float* __restrict__ qmask,
        const float* __restrict__ Ksum, const float* __restrict__ rowmax,
        const float* __restrict__ W, const float* __restrict__ b,
        float* __restrict__ out) {
    int t = threadIdx.x;
    int lane = t & 63;
    int wid = (blockIdx.x << 2) | (t >> 6);    // global (n,l,h) index
    int n = wid / (L_ * H_);
    int lh = wid % (L_ * H_);
    int l = lh / H_, h = lh % H_;

    float q = Q[(size_t)wid * 64 + lane];
    float qm = qmask[n * L_ + l];
    float p = feat(q) * qm * Ksum[(n * H_ + h) * 64 + lane];
    #pragma unroll
    for (int off = 32; off > 0; off >>= 1)
        p += __shfl_xor(p, off, 64);
    float mean = p * (1.0f / S_);
    float mx = rowmax[((size_t)n * H_ + h) * L_ + l];
    float zz = W[0] * mean + W[1] * mx + b[0];
    float g = 1.0f / (1.0f + __expf(-zz));
    out[(size_t)wid * 64 + lane] = q * qm * g;
}

extern "C" void kernel_launch(void* const* d_in, const int* in_sizes, int n_in,
                              void* d_out, int out_size, void* d_ws, size_t ws_size,
                              hipStream_t stream) {
    const float* Q      = (const float*)d_in[0];
    const float* K      = (const float*)d_in[1];
    // d_in[2] = values: masked in reference but unused downstream
    const float* qmask  = (const float*)d_in[3];
    const float* kvmask = (const float*)d_in[4];
    const float* W      = (const float*)d_in[5];
    const float* b      = (const float*)d_in[6];
    float* out = (float*)d_out;

    float* Ksum   = (float*)d_ws;            // N*H*D = 1024 floats
    float* rowmax = (float*)d_ws + 1024;     // N*H*L = 32768 floats

    hipMemsetAsync(Ksum, 0, 1024 * sizeof(float), stream);
    hipMemsetAsync(rowmax, 0, (size_t)N_ * H_ * L_ * sizeof(float), stream);

    ksum_kernel<<<dim3(N_ * H_, 8), 256, 0, stream>>>(K, kvmask, Ksum);
    rowmax_kernel<<<dim3(L_ / BL, N_ * H_, SSPLIT), 256, 0, stream>>>(
        Q, K, qmask, kvmask, rowmax);
    finalize_kernel<<<dim3(N_ * L_ * H_ / 4), 256, 0, stream>>>(
        Q, qmask, Ksum, rowmax, W, b, out);
}

// Round 2
// 123.474 us; speedup vs baseline: 2.0520x; 2.0520x over previous
//
#include <hip/hip_runtime.h>
#include <math.h>

#define N_ 2
#define L_ 2048
#define S_ 2048
#define H_ 8
#define D_ 64

#define BLK_L 256        // l-rows per block (4 waves x 64)
#define BS 64            // s-rows per K tile
#define SSPLIT 4
#define KPAD 72          // 64 + 8 bf16 pad: 144B row stride, 16B aligned, 2-way banks

typedef __attribute__((ext_vector_type(8))) short short8;
typedef __attribute__((ext_vector_type(4))) float floatx4;

__device__ __forceinline__ float feat(float x) {
    // elu(x)+1 = x>0 ? x+1 : exp(x)
    return x > 0.0f ? x + 1.0f : __expf(x);
}
__device__ __forceinline__ short f2bf(float x) {
    unsigned u = __float_as_uint(x);
    unsigned r = (u + 0x7fffu + ((u >> 16) & 1u)) >> 16;   // round-nearest-even
    return (short)r;
}
__device__ __forceinline__ float bf2f(short h) {
    return __uint_as_float(((unsigned)(unsigned short)h) << 16);
}

__global__ __launch_bounds__(256) void ksum_kernel(const float* __restrict__ K,
        const float* __restrict__ kvmask, float* __restrict__ Ksum) {
    int nh = blockIdx.x;
    int z = blockIdx.y;           // 32 chunks of 64 s-rows
    int n = nh >> 3, h = nh & 7;
    int t = threadIdx.x;
    int d = t & 63, sc = t >> 6;  // sc in 0..3
    float sum = 0.f;
    int s0 = z * 64 + sc * 16;
    #pragma unroll
    for (int k = 0; k < 16; ++k) {
        int s = s0 + k;
        float v = K[(((size_t)n * S_ + s) * H_ + h) * D_ + d];
        sum += feat(v) * kvmask[n * S_ + s];
    }
    __shared__ float sm[256];
    sm[t] = sum;
    __syncthreads();
    if (t < 64) {
        float tot = sm[t] + sm[t + 64] + sm[t + 128] + sm[t + 192];
        atomicAdd(&Ksum[nh * 64 + t], tot);
    }
}

__global__ __launch_bounds__(256) void rowmax_mfma(
        const float* __restrict__ Q, const float* __restrict__ K,
        const float* __restrict__ qmask, const float* __restrict__ kvmask,
        float* __restrict__ rowmaxg) {
    __shared__ short Kh[BS * KPAD];
    __shared__ short Kl[BS * KPAD];

    int nh = blockIdx.y;
    int n = nh >> 3, h = nh & 7;
    int t = threadIdx.x;
    int w = t >> 6, lane = t & 63;
    int quad = lane >> 4, l16 = lane & 15;
    int lblock = blockIdx.x * BLK_L;
    int z = blockIdx.z;

    // ---- preload A fragments (featurized Q, bf16 hi/lo split) into registers ----
    // A-frag layout (16x16x32): m = lane&15, k = quad*8 + j
    short8 Ah[4][2], Al[4][2];
    #pragma unroll
    for (int lsub = 0; lsub < 4; ++lsub) {
        int lrow = lblock + w * 64 + lsub * 16 + l16;
        float qm = qmask[n * L_ + lrow];
        const float* qp = Q + (((size_t)n * L_ + lrow) * H_ + h) * D_ + quad * 8;
        #pragma unroll
        for (int ks = 0; ks < 2; ++ks) {
            float4 v0 = *(const float4*)(qp + ks * 32);
            float4 v1 = *(const float4*)(qp + ks * 32 + 4);
            float fv[8];
            fv[0] = feat(v0.x) * qm; fv[1] = feat(v0.y) * qm;
            fv[2] = feat(v0.z) * qm; fv[3] = feat(v0.w) * qm;
            fv[4] = feat(v1.x) * qm; fv[5] = feat(v1.y) * qm;
            fv[6] = feat(v1.z) * qm; fv[7] = feat(v1.w) * qm;
            short8 hi, lo;
            #pragma unroll
            for (int j = 0; j < 8; ++j) {
                short hb = f2bf(fv[j]);
                hi[j] = hb;
                lo[j] = f2bf(fv[j] - bf2f(hb));
            }
            Ah[lsub][ks] = hi;
            Al[lsub][ks] = lo;
        }
    }

    float rmax[4][4];
    #pragma unroll
    for (int i = 0; i < 4; ++i)
        #pragma unroll
        for (int r = 0; r < 4; ++r) rmax[i][r] = 0.f;   // dots >= 0

    const int tiles = S_ / SSPLIT / BS;    // 8
    for (int tile = 0; tile < tiles; ++tile) {
        int sbase = z * (S_ / SSPLIT) + tile * BS;
        __syncthreads();                   // previous tile's LDS reads done
        // ---- stage K tile: featurize + hi/lo split -> LDS ----
        {
            int row = t >> 2, chunk = t & 3;
            float km = kvmask[n * S_ + sbase + row];
            const float* kp = K + (((size_t)n * S_ + sbase + row) * H_ + h) * D_ + chunk * 16;
            float fv[16];
            #pragma unroll
            for (int j = 0; j < 4; ++j) {
                float4 v = *(const float4*)(kp + j * 4);
                fv[4 * j + 0] = feat(v.x) * km;
                fv[4 * j + 1] = feat(v.y) * km;
                fv[4 * j + 2] = feat(v.z) * km;
                fv[4 * j + 3] = feat(v.w) * km;
            }
            short8 h0, h1, l0, l1;
            #pragma unroll
            for (int j = 0; j < 8; ++j) {
                short hb = f2bf(fv[j]);
                h0[j] = hb;
                l0[j] = f2bf(fv[j] - bf2f(hb));
                short hb2 = f2bf(fv[8 + j]);
                h1[j] = hb2;
                l1[j] = f2bf(fv[8 + j] - bf2f(hb2));
            }
            short* dh = &Kh[row * KPAD + chunk * 16];
            short* dl = &Kl[row * KPAD + chunk * 16];
            *(short8*)(dh)     = h0;
            *(short8*)(dh + 8) = h1;
            *(short8*)(dl)     = l0;
            *(short8*)(dl + 8) = l1;
        }
        __syncthreads();

        // ---- MFMA: C = Qf . Kf^T, rowmax ----
        #pragma unroll
        for (int ssub = 0; ssub < 4; ++ssub) {
            // B-frag layout: n = lane&15 (s row of K), k = quad*8 + j
            const short* bph = &Kh[(ssub * 16 + l16) * KPAD + quad * 8];
            const short* bpl = &Kl[(ssub * 16 + l16) * KPAD + quad * 8];
            short8 Bh0 = *(const short8*)(bph);
            short8 Bh1 = *(const short8*)(bph + 32);
            short8 Bl0 = *(const short8*)(bpl);
            short8 Bl1 = *(const short8*)(bpl + 32);
            #pragma unroll
            for (int lsub = 0; lsub < 4; ++lsub) {
                floatx4 acc = {0.f, 0.f, 0.f, 0.f};
                acc = __builtin_amdgcn_mfma_f32_16x16x32_bf16(Ah[lsub][0], Bh0, acc, 0, 0, 0);
                acc = __builtin_amdgcn_mfma_f32_16x16x32_bf16(Ah[lsub][1], Bh1, acc, 0, 0, 0);
                acc = __builtin_amdgcn_mfma_f32_16x16x32_bf16(Ah[lsub][0], Bl0, acc, 0, 0, 0);
                acc = __builtin_amdgcn_mfma_f32_16x16x32_bf16(Ah[lsub][1], Bl1, acc, 0, 0, 0);
                acc = __builtin_amdgcn_mfma_f32_16x16x32_bf16(Al[lsub][0], Bh0, acc, 0, 0, 0);
                acc = __builtin_amdgcn_mfma_f32_16x16x32_bf16(Al[lsub][1], Bh1, acc, 0, 0, 0);
                #pragma unroll
                for (int r = 0; r < 4; ++r)
                    rmax[lsub][r] = fmaxf(rmax[lsub][r], acc[r]);
            }
        }
    }

    // ---- epilogue: reduce rowmax across the 16 column-lanes, atomicMax ----
    // C/D layout: col(s) = lane&15, row(l) = quad*4 + r
    #pragma unroll
    for (int lsub = 0; lsub < 4; ++lsub)
        #pragma unroll
        for (int r = 0; r < 4; ++r) {
            float m = rmax[lsub][r];
            m = fmaxf(m, __shfl_xor(m, 1, 64));
            m = fmaxf(m, __shfl_xor(m, 2, 64));
            m = fmaxf(m, __shfl_xor(m, 4, 64));
            m = fmaxf(m, __shfl_xor(m, 8, 64));
            if (l16 == 0) {
                int l = lblock + w * 64 + lsub * 16 + quad * 4 + r;
                atomicMax((unsigned*)&rowmaxg[(size_t)nh * L_ + l],
                          __float_as_uint(m));
            }
        }
}

__global__ __launch_bounds__(256) void finalize_kernel(
        const float* __restrict__ Q, const float* __restrict__ qmask,
        const float* __restrict__ Ksum, const float* __restrict__ rowmaxg,
        const float* __restrict__ W, const float* __restrict__ b,
        float* __restrict__ out) {
    int t = threadIdx.x;
    int lane = t & 63;
    int wid = (blockIdx.x << 2) | (t >> 6);    // global (n,l,h) index
    int n = wid / (L_ * H_);
    int lh = wid % (L_ * H_);
    int l = lh / H_, h = lh % H_;

    float q = Q[(size_t)wid * 64 + lane];
    float qm = qmask[n * L_ + l];
    float p = feat(q) * qm * Ksum[(n * H_ + h) * 64 + lane];
    #pragma unroll
    for (int off = 32; off > 0; off >>= 1)
        p += __shfl_xor(p, off, 64);
    float mean = p * (1.0f / S_);
    float mx = rowmaxg[((size_t)n * H_ + h) * L_ + l];
    float zz = W[0] * mean + W[1] * mx + b[0];
    float g = 1.0f / (1.0f + __expf(-zz));
    out[(size_t)wid * 64 + lane] = q * qm * g;
}

extern "C" void kernel_launch(void* const* d_in, const int* in_sizes, int n_in,
                              void* d_out, int out_size, void* d_ws, size_t ws_size,
                              hipStream_t stream) {
    const float* Q      = (const float*)d_in[0];
    const float* K      = (const float*)d_in[1];
    // d_in[2] = values: masked in reference but unused downstream
    const float* qmask  = (const float*)d_in[3];
    const float* kvmask = (const float*)d_in[4];
    const float* W      = (const float*)d_in[5];
    const float* b      = (const float*)d_in[6];
    float* out = (float*)d_out;

    float* Ksum   = (float*)d_ws;            // N*H*D = 1024 floats
    float* rowmax = (float*)d_ws + 1024;     // N*H*L = 32768 floats

    hipMemsetAsync(Ksum, 0, 1024 * sizeof(float), stream);
    hipMemsetAsync(rowmax, 0, (size_t)N_ * H_ * L_ * sizeof(float), stream);

    ksum_kernel<<<dim3(N_ * H_, 32), 256, 0, stream>>>(K, kvmask, Ksum);
    rowmax_mfma<<<dim3(L_ / BLK_L, N_ * H_, SSPLIT), 256, 0, stream>>>(
        Q, K, qmask, kvmask, rowmax);
    finalize_kernel<<<dim3(N_ * L_ * H_ / 4), 256, 0, stream>>>(
        Q, qmask, Ksum, rowmax, W, b, out);
}